// Round 4
// baseline (380.562 us; speedup 1.0000x reference)
//
#include <hip/hip_runtime.h>
#include <hip/hip_fp16.h>

static constexpr int NN  = 10000;    // nodes
static constexpr int NE  = 640000;   // edges
static constexpr int INC = 128;
static constexpr int HIDC = 256;
static constexpr int OUTC = 128;
static constexpr int CAP = 128;      // ELL row capacity (max in-degree ~104)

static constexpr int NB = 512;       // persistent blocks: 2 per CU (LDS 40KB->4/CU, VGPR<=64 -> 8 waves/SIMD)
static constexpr int FB = 128;       // count/fill slices (5000 edges each)
static constexpr int CB = 64;        // csum slices (10000 edges each)
static constexpr int NP = 10240;     // padded node stride
static constexpr int AJ = 2500;      // agg jobs (4 nodes each)
static constexpr int RJ = 40;        // csum reduce jobs
static constexpr int NG = 625;       // 16-node gemm groups

typedef _Float16 half8 __attribute__((ext_vector_type(8)));
typedef float f32x4 __attribute__((ext_vector_type(4)));

// ---- workspace layout (bytes); first 2048 zeroed by hipMemsetAsync ----
static constexpr size_t OFF_BAR   = 0;          // uint[1] barrier counter (monotonic)
static constexpr size_t OFF_V     = 64;         // float[256]
static constexpr size_t ZERO_B    = 2048;
static constexpr size_t OFF_CNT   = 2048;       // int[10240]
static constexpr size_t OFF_DINV  = 43008;      // float[10240]
static constexpr size_t OFF_CSUM  = 83968;      // float[10240]
static constexpr size_t OFF_ELL   = 124928;     // ushort[10000*128] (j-permuted)
static constexpr size_t OFF_XH    = 2684928;    // half[10000*128]
static constexpr size_t OFF_XA    = 5244928;    // half[10000*128]
static constexpr size_t OFF_CPART = 7804928;    // ushort[128*10240]
static constexpr size_t OFF_CSP   = 10426368;   // float[64*10240]
static constexpr size_t OFF_W1T   = 13047808;   // half[256*128]

// Grid barrier, fixed from R3: poll with RELAXED agent atomic load (sc1 read
// from the coherence point, NO buffer_inv per poll — R3's ACQUIRE polling
// invalidated the shared per-XCD L2 every ~50ns and starved the machine).
// Exactly one ACQUIRE (one L2 invalidate) after the target is reached;
// RELEASE on the increment writes back this XCD's dirty lines.
__device__ __forceinline__ void gbar(unsigned int* bar, unsigned int target) {
    __syncthreads();
    if (threadIdx.x == 0) {
        __hip_atomic_fetch_add(bar, 1u, __ATOMIC_RELEASE, __HIP_MEMORY_SCOPE_AGENT);
        while (__hip_atomic_load(bar, __ATOMIC_RELAXED, __HIP_MEMORY_SCOPE_AGENT) < target)
            __builtin_amdgcn_s_sleep(8);
        (void)__hip_atomic_load(bar, __ATOMIC_ACQUIRE, __HIP_MEMORY_SCOPE_AGENT);
    }
    __syncthreads();
}

__global__ __launch_bounds__(1024, 8) void k_all(
    const int* __restrict__ ei, const float* __restrict__ x,
    const float* __restrict__ W1, const float* __restrict__ b1,
    const float* __restrict__ W2, const float* __restrict__ b2,
    const float* __restrict__ fcw, const float* __restrict__ fcb,
    float* __restrict__ out,
    unsigned int* __restrict__ bar, float* __restrict__ v,
    int* __restrict__ cnt, float* __restrict__ dinv,
    float* __restrict__ csum, unsigned short* __restrict__ ell,
    __half* __restrict__ xh, __half* __restrict__ xa,
    unsigned short* __restrict__ cpart, float* __restrict__ cspart,
    __half* __restrict__ w1t)
{
    __shared__ int lh[NN];           // 40 KB, reused by every phase
    const int t = threadIdx.x, b = blockIdx.x;

    // ======== P1: degree count (LDS histogram, slices 0..127) | W1^T ========
    if (b < FB) {
        for (int i = t; i < NN; i += 1024) lh[i] = 0;
        __syncthreads();
        int e0 = b * (NE / FB);
        for (int k = t; k < NE / FB; k += 1024) atomicAdd(&lh[ei[NE + e0 + k]], 1);
        __syncthreads();
        for (int i = t; i < NN; i += 1024) cpart[b * NP + i] = (unsigned short)lh[i];
    } else if (b < FB + 32) {
        int gid = (b - FB) * 1024 + t;
        int k = gid & 127, tc = gid >> 7;
        w1t[tc * INC + k] = __float2half(W1[k * HIDC + tc]);
    }
    gbar(bar, 1 * NB);

    // ======== P2: coalesced serial scan (40 blocks x 256 threads) ========
    if (b < 40 && t < 256) {
        int n = b * 256 + t;
        if (n < NN) {
            int run = 0;
#pragma unroll 8
            for (int bb = 0; bb < FB; bb++) {
                int c = cpart[bb * NP + n];
                cpart[bb * NP + n] = (unsigned short)run;
                run += c;
            }
            cnt[n] = run;
            dinv[n] = rsqrtf((float)(1 + run));   // +1 self loop
        }
    }
    gbar(bar, 2 * NB);

    // ======== P3: ELL fill (LDS cursor = offset) | csum partials | xh ========
    if (b < FB) {
        for (int i = t; i < NN; i += 1024) lh[i] = (int)cpart[b * NP + i];
        __syncthreads();
        int e0 = b * (NE / FB);
        for (int k = t; k < NE / FB; k += 1024) {
            int s = ei[e0 + k];
            int d = ei[NE + e0 + k];
            int pos = atomicAdd(&lh[d], 1);       // absolute position
            if (pos < CAP)
                ell[d * CAP + (pos & 3) * 32 + (pos >> 2)] = (unsigned short)s;
        }
    } else if (b < FB + CB) {
        int bb = b - FB;
        float* lc = (float*)lh;
        for (int i = t; i < NN; i += 1024) lc[i] = 0.f;
        __syncthreads();
        int e0 = bb * (NE / CB);
        for (int k = t; k < NE / CB; k += 1024) {
            int s = ei[e0 + k];
            int d = ei[NE + e0 + k];
            atomicAdd(&lc[s], dinv[d]);
        }
        __syncthreads();
        for (int i = t; i < NN; i += 1024) cspart[bb * NP + i] = lc[i];
    } else {
        // xh[n,:] = fp16( dinv[n] * X[n,:] );  320 jobs x 1000 float4
        int jid = b - FB - CB;                    // 0..319
        if (t < 1000) {
            const float4* x4 = (const float4*)x;
            int i4 = jid * 1000 + t;
            if (i4 < NN * (INC / 4)) {
                float4 vv = x4[i4];
                float dv = dinv[i4 >> 5];
                __half2 o[2] = {__floats2half2_rn(dv * vv.x, dv * vv.y),
                                __floats2half2_rn(dv * vv.z, dv * vv.w)};
                *(float2*)(xh + i4 * 4) = *(float2*)o;
            }
        }
    }
    gbar(bar, 3 * NB);

    // ======== P4: aggregation gather (proven loop) + csum reduce ========
    {
        int t256 = t & 255;
        int vb = b * 4 + (t >> 8);               // 2048 virtual 256-thread blocks
        for (int job = vb; job < AJ + RJ; job += 4 * NB) {
            if (job < AJ) {
                int lane = t256 & 63;
                int n = job * 4 + (t256 >> 6);
                int g = lane & 15;
                int j = lane >> 4;
                float dn = dinv[n];
                float acc[8];
#pragma unroll
                for (int k = 0; k < 8; k++) acc[k] = 0.f;
                if (j == 0) {                     // self loop from fp32 X
                    const float4* x4 = (const float4*)x;
                    float4 a = x4[n * 32 + 2 * g];
                    float4 c4 = x4[n * 32 + 2 * g + 1];
                    acc[0] = dn * a.x;  acc[1] = dn * a.y;  acc[2] = dn * a.z;  acc[3] = dn * a.w;
                    acc[4] = dn * c4.x; acc[5] = dn * c4.y; acc[6] = dn * c4.z; acc[7] = dn * c4.w;
                }
                int c = cnt[n];
                int base = n * CAP;
                for (int i = 0; i < c; i += 32) {
                    uint4 ev = *(const uint4*)(ell + base + j * 32 + (i >> 2));
                    unsigned raw[8] = {ev.x & 0xffffu, ev.x >> 16, ev.y & 0xffffu, ev.y >> 16,
                                       ev.z & 0xffffu, ev.z >> 16, ev.w & 0xffffu, ev.w >> 16};
                    int   su[8];
                    float ws8[8];
                    float4 xv[8];
#pragma unroll
                    for (int u = 0; u < 8; u++) {
                        int idx = i + 4 * u + j;
                        bool act = idx < c;
                        su[u] = act ? (int)raw[u] : n;
                        ws8[u] = act ? 1.f : 0.f;
                    }
#pragma unroll
                    for (int u = 0; u < 8; u++)
                        xv[u] = *(const float4*)(xh + su[u] * INC + 8 * g);
#pragma unroll
                    for (int u = 0; u < 8; u++) {
                        const __half2* h2 = (const __half2*)&xv[u];
#pragma unroll
                        for (int q = 0; q < 4; q++) {
                            float2 f = __half22float2(h2[q]);
                            acc[2 * q]     = fmaf(ws8[u], f.x, acc[2 * q]);
                            acc[2 * q + 1] = fmaf(ws8[u], f.y, acc[2 * q + 1]);
                        }
                    }
                }
#pragma unroll
                for (int k = 0; k < 8; k++) {
                    acc[k] += __shfl_down(acc[k], 32);
                    acc[k] += __shfl_down(acc[k], 16);
                }
                if (j == 0) {
                    __half2 o[4];
#pragma unroll
                    for (int q = 0; q < 4; q++)
                        o[q] = __floats2half2_rn(dn * acc[2 * q], dn * acc[2 * q + 1]);
                    *(float4*)(xa + n * INC + 8 * g) = *(float4*)o;
                }
            } else {
                int n = (job - AJ) * 256 + t256;
                if (n < NN) {
                    float s = 0.f;
#pragma unroll
                    for (int bb = 0; bb < CB; bb++) s += cspart[bb * NP + n];
                    csum[n] = s;
                }
            }
        }
    }
    gbar(bar, 4 * NB);

    // ======== P5: MFMA gemm, 4 groups per block (quarters) ========
    {
        float* vloc = (float*)lh;                 // [4][256]
        vloc[t] = 0.f;
        __syncthreads();
        int q = t >> 8, t256 = t & 255;
        int gidx = b * 4 + q;
        if (gidx < NG) {
            int lane = t256 & 63;
            int w = t256 >> 6;                    // wave within quarter: cols [64w,64w+64)
            int m = lane & 15;
            int quad = lane >> 4;
            float bcol[4];
#pragma unroll
            for (int tt = 0; tt < 4; tt++) bcol[tt] = b1[w * 64 + tt * 16 + m];
            const half8* xa8 = (const half8*)xa;
            const half8* w8  = (const half8*)w1t;
            int base = gidx * 16;
            f32x4 acc[4] = {{0,0,0,0},{0,0,0,0},{0,0,0,0},{0,0,0,0}};
#pragma unroll
            for (int k0 = 0; k0 < 4; k0++) {
                half8 af = xa8[(base + m) * 16 + k0 * 4 + quad];
#pragma unroll
                for (int tt = 0; tt < 4; tt++) {
                    int col = w * 64 + tt * 16 + m;
                    half8 bf = w8[col * 16 + k0 * 4 + quad];
                    acc[tt] = __builtin_amdgcn_mfma_f32_16x16x32_f16(af, bf, acc[tt], 0, 0, 0);
                }
            }
            float cr[4];
#pragma unroll
            for (int r = 0; r < 4; r++) {
                int n = base + quad * 4 + r;
                float dnn = dinv[n];
                cr[r] = dnn * (dnn + csum[n]);
            }
#pragma unroll
            for (int tt = 0; tt < 4; tt++) {
                float p = 0.f;
#pragma unroll
                for (int r = 0; r < 4; r++)
                    p += cr[r] * fmaxf(acc[tt][r] + bcol[tt], 0.f);
                p += __shfl_down(p, 16);
                p += __shfl_down(p, 32);
                if (lane < 16) vloc[q * 256 + w * 64 + tt * 16 + lane] = p;
            }
        }
        __syncthreads();
        if (t < 256 && b * 4 < NG) {
            float s = vloc[t] + vloc[256 + t] + vloc[512 + t] + vloc[768 + t];
            atomicAdd(&v[t], s);
        }
    }
    gbar(bar, 5 * NB);

    // ======== P6: finale (block 0) ========
    if (b == 0) {
        float* red = (float*)lh;
        if (t < 256) {
            float vt = __hip_atomic_load(&v[t], __ATOMIC_ACQUIRE, __HIP_MEMORY_SCOPE_AGENT);
            float u = 0.f;
#pragma unroll 4
            for (int jj = 0; jj < OUTC; jj++) u = fmaf(W2[t * OUTC + jj], fcw[jj], u);
            float contrib = vt * u * (1.0f / (float)NN);
            if (t < OUTC) contrib += b2[t] * fcw[t];
            red[t] = contrib;
        }
        __syncthreads();
        for (int s = 128; s > 0; s >>= 1) {
            if (t < s) red[t] += red[t + s];
            __syncthreads();
        }
        if (t == 0) out[0] = red[0] + fcb[0];
    }
}

extern "C" void kernel_launch(void* const* d_in, const int* in_sizes, int n_in,
                              void* d_out, int out_size, void* d_ws, size_t ws_size,
                              hipStream_t stream) {
    const float* x   = (const float*)d_in[0];
    const int*   ei  = (const int*)d_in[1];
    const float* W1  = (const float*)d_in[2];
    const float* b1  = (const float*)d_in[3];
    const float* W2  = (const float*)d_in[4];
    const float* b2  = (const float*)d_in[5];
    const float* fcw = (const float*)d_in[6];
    const float* fcb = (const float*)d_in[7];
    float* out = (float*)d_out;

    char* ws = (char*)d_ws;
    unsigned int*   bar    = (unsigned int*)(ws + OFF_BAR);
    float*          v      = (float*)(ws + OFF_V);
    int*            cnt    = (int*)(ws + OFF_CNT);
    float*          dinv   = (float*)(ws + OFF_DINV);
    float*          csum   = (float*)(ws + OFF_CSUM);
    unsigned short* ell    = (unsigned short*)(ws + OFF_ELL);
    __half*         xh     = (__half*)(ws + OFF_XH);
    __half*         xa     = (__half*)(ws + OFF_XA);
    unsigned short* cpart  = (unsigned short*)(ws + OFF_CPART);
    float*          cspart = (float*)(ws + OFF_CSP);
    __half*         w1t    = (__half*)(ws + OFF_W1T);

    hipMemsetAsync(ws, 0, ZERO_B, stream);       // bar + v
    k_all<<<NB, 1024, 0, stream>>>(ei, x, W1, b1, W2, b2, fcw, fcb, out,
                                   bar, v, cnt, dinv, csum, ell, xh, xa,
                                   cpart, cspart, w1t);
}

// Round 5
// 148.681 us; speedup vs baseline: 2.5596x; 2.5596x over previous
//
#include <hip/hip_runtime.h>
#include <hip/hip_fp16.h>

static constexpr int NN  = 10000;    // nodes
static constexpr int NE  = 640000;   // edges
static constexpr int INC = 128;
static constexpr int HIDC = 256;
static constexpr int OUTC = 128;
static constexpr int CAP = 128;      // ELL row capacity (max in-degree ~104)

static constexpr int FB = 128;       // fill/count slice blocks (5000 edges each)
static constexpr int CB = 64;        // csum slice blocks (10000 edges each)
static constexpr int HB = 313;       // half-scale blocks (1024 thr * 4 floats)
static constexpr int TB = 32;        // W1 transpose blocks (now in k_count grid)
static constexpr int AB = 2500;      // agg blocks (4 nodes each)
static constexpr int NP = 10240;     // padded node stride
static constexpr int GG = 256;       // gemm blocks
static constexpr int NG = 625;       // 16-node groups

typedef _Float16 half8 __attribute__((ext_vector_type(8)));
typedef float f32x4 __attribute__((ext_vector_type(4)));

// ---- workspace layout (bytes); ws_size ~256 MB ----
static constexpr size_t OFF_DONE  = 0;          // uint[1]
static constexpr size_t OFF_V     = 64;         // float[256]
static constexpr size_t OFF_CNT   = 2048;       // int[10240]
static constexpr size_t OFF_DINV  = 43008;      // float[10240]
static constexpr size_t OFF_CSUM  = 83968;      // float[10240]
static constexpr size_t OFF_ELL   = 124928;     // ushort[10000*128] (j-permuted)
static constexpr size_t OFF_XH    = 2684928;    // half[10000*128]
static constexpr size_t OFF_XA    = 5244928;    // half[10000*128]
static constexpr size_t OFF_CPART = 7804928;    // ushort[128*10240]
static constexpr size_t OFF_CSP   = 10426368;   // float[64*10240]
static constexpr size_t OFF_W1T   = 13047808;   // half[256*128]

// ---- K1: slice-parallel degree count (LDS histogram) | W1^T transpose.
// int4 edge loads (4 edges/thread/iter). Block 0 also zeroes v/done
// (consumed only by k_gemm, three dispatches later in stream order). ----
__global__ __launch_bounds__(1024) void k_count(const int* __restrict__ ei,
                                                const float* __restrict__ W1,
                                                unsigned short* __restrict__ cpart,
                                                __half* __restrict__ w1t,
                                                float* __restrict__ v,
                                                unsigned int* __restrict__ done) {
    __shared__ int lh[NN];
    int t = threadIdx.x, b = blockIdx.x;
    if (b >= FB) {            // W1^T: 32 blocks, 256*128 entries
        int gid = (b - FB) * 1024 + t;
        int k = gid & 127, tc = gid >> 7;
        w1t[tc * INC + k] = __float2half(W1[k * HIDC + tc]);
        return;
    }
    if (b == 0) {
        if (t < 256) v[t] = 0.f;
        if (t == 256) *done = 0u;
    }
    for (int i = t; i < NN; i += 1024) lh[i] = 0;
    __syncthreads();
    int e0 = b * (NE / FB);
    const int4* d4 = (const int4*)(ei + NE + e0);
    for (int k = t; k < (NE / FB) / 4; k += 1024) {
        int4 dd = d4[k];
        atomicAdd(&lh[dd.x], 1);
        atomicAdd(&lh[dd.y], 1);
        atomicAdd(&lh[dd.z], 1);
        atomicAdd(&lh[dd.w], 1);
    }
    __syncthreads();
    for (int i = t; i < NN; i += 1024) cpart[b * NP + i] = (unsigned short)lh[i];
}

// ---- K2: per-node scan of partials -> per-block offsets, cnt, dinv.
// Coalesced: thread n reads cpart[b][n], consecutive threads contiguous.
// 40x256 (vs 10x1024) spreads the same pattern over 4x the CUs. ----
__global__ __launch_bounds__(256) void k_scan(unsigned short* __restrict__ cpart,
                                              int* __restrict__ cnt,
                                              float* __restrict__ dinv) {
    int n = blockIdx.x * 256 + threadIdx.x;
    if (n >= NN) return;
    int run = 0;
#pragma unroll 8
    for (int b = 0; b < FB; b++) {
        int c = cpart[b * NP + n];
        cpart[b * NP + n] = (unsigned short)run;
        run += c;
    }
    cnt[n] = run;
    dinv[n] = rsqrtf((float)(1 + run));   // +1 self loop
}

// ---- K3 (fused): ELL fill (j-permuted) | csum partials | fp16 X ----
// ELL slot(pos) = (pos&3)*32 + (pos>>2): group-j entries for unroll-block i
// are contiguous at [j*32 + (i>>2), +8) -> one 16B load in k_agg.
// int4 edge loads; slot order within a node is irrelevant (sum-aggregate),
// and max in-degree ~104 < CAP so no truncation -> reorder is safe.
__global__ __launch_bounds__(1024) void k_prep(const int* __restrict__ ei,
                                               const float* __restrict__ x,
                                               const float* __restrict__ dinv,
                                               const unsigned short* __restrict__ cpart,
                                               unsigned short* __restrict__ ell,
                                               float* __restrict__ cspart,
                                               __half* __restrict__ xh) {
    __shared__ int lh[NN];
    __shared__ unsigned short soff[NN];
    int t = threadIdx.x, b = blockIdx.x;
    if (b < FB) {
        for (int i = t; i < NN; i += 1024) { lh[i] = 0; soff[i] = cpart[b * NP + i]; }
        __syncthreads();
        int e0 = b * (NE / FB);
        const int4* s4 = (const int4*)(ei + e0);
        const int4* d4 = (const int4*)(ei + NE + e0);
        for (int k = t; k < (NE / FB) / 4; k += 1024) {
            int4 s = s4[k];
            int4 d = d4[k];
            int ss[4] = {s.x, s.y, s.z, s.w};
            int dd[4] = {d.x, d.y, d.z, d.w};
#pragma unroll
            for (int u = 0; u < 4; u++) {
                int pos = (int)soff[dd[u]] + atomicAdd(&lh[dd[u]], 1);
                if (pos < CAP)
                    ell[dd[u] * CAP + (pos & 3) * 32 + (pos >> 2)] = (unsigned short)ss[u];
            }
        }
    } else if (b < FB + CB) {
        int bb = b - FB;
        float* lc = (float*)lh;
        for (int i = t; i < NN; i += 1024) lc[i] = 0.f;
        __syncthreads();
        int e0 = bb * (NE / CB);
        const int4* s4 = (const int4*)(ei + e0);
        const int4* d4 = (const int4*)(ei + NE + e0);
        for (int k = t; k < (NE / CB) / 4; k += 1024) {
            int4 s = s4[k];
            int4 d = d4[k];
            atomicAdd(&lc[s.x], dinv[d.x]);
            atomicAdd(&lc[s.y], dinv[d.y]);
            atomicAdd(&lc[s.z], dinv[d.z]);
            atomicAdd(&lc[s.w], dinv[d.w]);
        }
        __syncthreads();
        for (int i = t; i < NN; i += 1024) cspart[bb * NP + i] = lc[i];
    } else {
        // xh[n,:] = fp16( dinv[n] * X[n,:] )
        int gid = (b - FB - CB) * 1024 + t;
        int i = gid * 4;
        if (i < NN * INC) {
            float4 vv = *(const float4*)(x + i);
            float dv = dinv[i >> 7];
            __half2 o[2] = {__floats2half2_rn(dv * vv.x, dv * vv.y),
                            __floats2half2_rn(dv * vv.z, dv * vv.w)};
            *(float2*)(xh + i) = *(float2*)o;
        }
    }
}

// ---- K4 (fused): aggregation gather | csum reduce ----
// Xa[n] = fp16( dinv[n]*(dinv[n]*X[n] + sum_s xh[s]) ); xh pre-scaled by dinv[s].
// Wave=node; lane = g + 16*j; 8 rows in flight. ELL read = ONE 16B load per
// lane per iter (j-permuted layout). fp32 fmaf accumulate (proven form).
__global__ __launch_bounds__(256) void k_agg(const float* __restrict__ x,
                                             const __half* __restrict__ xh,
                                             const float* __restrict__ dinv,
                                             const int* __restrict__ cnt,
                                             const unsigned short* __restrict__ ell,
                                             const float* __restrict__ cspart,
                                             float* __restrict__ csum,
                                             __half* __restrict__ xa) {
    int b = blockIdx.x;
    if (b >= AB) {   // csum partial reduce (40 tail blocks)
        int n = (b - AB) * 256 + threadIdx.x;
        if (n < NN) {
            float s = 0.f;
#pragma unroll
            for (int bb = 0; bb < CB; bb++) s += cspart[bb * NP + n];
            csum[n] = s;
        }
        return;
    }
    int lane = threadIdx.x & 63;
    int n = b * 4 + (threadIdx.x >> 6);
    int g = lane & 15;        // 16B chunk of the 256B fp16 row
    int j = lane >> 4;        // neighbor group
    float dn = dinv[n];
    float acc[8];
#pragma unroll
    for (int k = 0; k < 8; k++) acc[k] = 0.f;
    if (j == 0) {             // self loop from fp32 X (outer dn applied at end)
        const float4* x4 = (const float4*)x;
        float4 a = x4[n * 32 + 2 * g];
        float4 c4 = x4[n * 32 + 2 * g + 1];
        acc[0] = dn * a.x;  acc[1] = dn * a.y;  acc[2] = dn * a.z;  acc[3] = dn * a.w;
        acc[4] = dn * c4.x; acc[5] = dn * c4.y; acc[6] = dn * c4.z; acc[7] = dn * c4.w;
    }
    int c = cnt[n];
    int base = n * CAP;
    for (int i = 0; i < c; i += 32) {
        // one 16B load: this j-group's 8 ELL entries for idx = i + 4u + j
        uint4 ev = *(const uint4*)(ell + base + j * 32 + (i >> 2));
        unsigned raw[8] = {ev.x & 0xffffu, ev.x >> 16, ev.y & 0xffffu, ev.y >> 16,
                           ev.z & 0xffffu, ev.z >> 16, ev.w & 0xffffu, ev.w >> 16};
        int   su[8];
        float ws[8];
        float4 xv[8];
#pragma unroll
        for (int u = 0; u < 8; u++) {
            int idx = i + 4 * u + j;
            bool act = idx < c;
            su[u] = act ? (int)raw[u] : n;   // in-bounds safe row when inactive
            ws[u] = act ? 1.f : 0.f;
        }
#pragma unroll
        for (int u = 0; u < 8; u++)
            xv[u] = *(const float4*)(xh + su[u] * INC + 8 * g);
#pragma unroll
        for (int u = 0; u < 8; u++) {
            const __half2* h2 = (const __half2*)&xv[u];
#pragma unroll
            for (int q = 0; q < 4; q++) {
                float2 f = __half22float2(h2[q]);
                acc[2 * q]     = fmaf(ws[u], f.x, acc[2 * q]);
                acc[2 * q + 1] = fmaf(ws[u], f.y, acc[2 * q + 1]);
            }
        }
    }
#pragma unroll
    for (int k = 0; k < 8; k++) {
        acc[k] += __shfl_down(acc[k], 32);
        acc[k] += __shfl_down(acc[k], 16);
    }
    if (j == 0) {
        __half2 o[4];
#pragma unroll
        for (int q = 0; q < 4; q++)
            o[q] = __floats2half2_rn(dn * acc[2 * q], dn * acc[2 * q + 1]);
        *(float4*)(xa + n * INC + 8 * g) = *(float4*)o;
    }
}

// ---- K5: MFMA GEMM + weighted-relu reduction + fused final scalar ----
__global__ __launch_bounds__(256) void k_gemm(const __half* __restrict__ xa,
                                              const __half* __restrict__ w1t,
                                              const float* __restrict__ b1,
                                              const float* __restrict__ dinv,
                                              const float* __restrict__ csum,
                                              float* __restrict__ v,
                                              unsigned int* __restrict__ done,
                                              const float* __restrict__ W2,
                                              const float* __restrict__ b2,
                                              const float* __restrict__ fcw,
                                              const float* __restrict__ fcb,
                                              float* __restrict__ out) {
    __shared__ float vloc[HIDC];
    int t = threadIdx.x;
    int w = t >> 6;           // wave id: owns cols [64w, 64w+64)
    int lane = t & 63;
    int m = lane & 15;
    int quad = lane >> 4;
    for (int i = t; i < HIDC; i += 256) vloc[i] = 0.f;
    __syncthreads();

    float bcol[4];
#pragma unroll
    for (int tt = 0; tt < 4; tt++) bcol[tt] = b1[w * 64 + tt * 16 + m];

    const half8* xa8 = (const half8*)xa;     // 8-half (16B) granules
    const half8* w8  = (const half8*)w1t;

    for (int gidx = blockIdx.x; gidx < NG; gidx += gridDim.x) {
        int base = gidx * 16;
        f32x4 acc[4] = {{0,0,0,0},{0,0,0,0},{0,0,0,0},{0,0,0,0}};
#pragma unroll
        for (int k0 = 0; k0 < 4; k0++) {
            half8 af = xa8[(base + m) * 16 + k0 * 4 + quad];
#pragma unroll
            for (int tt = 0; tt < 4; tt++) {
                int col = w * 64 + tt * 16 + m;
                half8 bf = w8[col * 16 + k0 * 4 + quad];
                acc[tt] = __builtin_amdgcn_mfma_f32_16x16x32_f16(af, bf, acc[tt], 0, 0, 0);
            }
        }
        float cr[4];
#pragma unroll
        for (int r = 0; r < 4; r++) {
            int n = base + quad * 4 + r;
            float dnn = dinv[n];
            cr[r] = dnn * (dnn + csum[n]);
        }
#pragma unroll
        for (int tt = 0; tt < 4; tt++) {
            float p = 0.f;
#pragma unroll
            for (int r = 0; r < 4; r++)
                p += cr[r] * fmaxf(acc[tt][r] + bcol[tt], 0.f);
            p += __shfl_down(p, 16);
            p += __shfl_down(p, 32);
            if (lane < 16) vloc[w * 64 + tt * 16 + lane] += p;  // wave-disjoint cols
        }
    }
    __syncthreads();
    atomicAdd(&v[t], vloc[t]);      // device-scope, distributed across blocks
    __threadfence();
    __shared__ bool last;
    if (t == 0) {
        unsigned int old = __hip_atomic_fetch_add(done, 1u, __ATOMIC_ACQ_REL,
                                                  __HIP_MEMORY_SCOPE_AGENT);
        last = (old == gridDim.x - 1);
    }
    __syncthreads();
    if (!last) return;
    // out = (1/N)*sum_t v[t]*u[t] + b2.fc_w + fc_b,  u = W2.fc_w
    float vt = __hip_atomic_load(&v[t], __ATOMIC_ACQUIRE, __HIP_MEMORY_SCOPE_AGENT);
    __shared__ float red[256];
    float u = 0.f;
#pragma unroll 4
    for (int jj = 0; jj < OUTC; jj++) u = fmaf(W2[t * OUTC + jj], fcw[jj], u);
    float contrib = vt * u * (1.0f / (float)NN);
    if (t < OUTC) contrib += b2[t] * fcw[t];
    red[t] = contrib;
    __syncthreads();
    for (int s = 128; s > 0; s >>= 1) {
        if (t < s) red[t] += red[t + s];
        __syncthreads();
    }
    if (t == 0) out[0] = red[0] + fcb[0];
}

extern "C" void kernel_launch(void* const* d_in, const int* in_sizes, int n_in,
                              void* d_out, int out_size, void* d_ws, size_t ws_size,
                              hipStream_t stream) {
    const float* x   = (const float*)d_in[0];
    const int*   ei  = (const int*)d_in[1];
    const float* W1  = (const float*)d_in[2];
    const float* b1  = (const float*)d_in[3];
    const float* W2  = (const float*)d_in[4];
    const float* b2  = (const float*)d_in[5];
    const float* fcw = (const float*)d_in[6];
    const float* fcb = (const float*)d_in[7];
    float* out = (float*)d_out;

    char* ws = (char*)d_ws;
    unsigned int*   done   = (unsigned int*)(ws + OFF_DONE);
    float*          v      = (float*)(ws + OFF_V);
    int*            cnt    = (int*)(ws + OFF_CNT);
    float*          dinv   = (float*)(ws + OFF_DINV);
    float*          csum   = (float*)(ws + OFF_CSUM);
    unsigned short* ell    = (unsigned short*)(ws + OFF_ELL);
    __half*         xh     = (__half*)(ws + OFF_XH);
    __half*         xa     = (__half*)(ws + OFF_XA);
    unsigned short* cpart  = (unsigned short*)(ws + OFF_CPART);
    float*          cspart = (float*)(ws + OFF_CSP);
    __half*         w1t    = (__half*)(ws + OFF_W1T);

    k_count<<<FB + TB, 1024, 0, stream>>>(ei, W1, cpart, w1t, v, done);
    k_scan<<<40, 256, 0, stream>>>(cpart, cnt, dinv);
    k_prep<<<FB + CB + HB, 1024, 0, stream>>>(ei, x, dinv, cpart, ell,
                                              cspart, xh);
    k_agg<<<AB + 40, 256, 0, stream>>>(x, xh, dinv, cnt, ell, cspart, csum, xa);
    k_gemm<<<GG, 256, 0, stream>>>(xa, w1t, b1, dinv, csum, v, done,
                                   W2, b2, fcw, fcb, out);
}

// Round 6
// 145.633 us; speedup vs baseline: 2.6132x; 1.0209x over previous
//
#include <hip/hip_runtime.h>
#include <hip/hip_fp16.h>

static constexpr int NN  = 10000;    // nodes
static constexpr int NE  = 640000;   // edges
static constexpr int INC = 128;
static constexpr int HIDC = 256;
static constexpr int OUTC = 128;
static constexpr int CAP = 128;      // ELL row capacity (max in-degree ~104)

static constexpr int FB = 128;       // fill/count slice blocks (5000 edges each)
static constexpr int CB = 64;        // csum slice blocks (10000 edges each)
static constexpr int HB = 313;       // half-scale blocks (1024 thr * 4 floats)
static constexpr int TB = 32;        // W1 transpose blocks (in k_count grid)
static constexpr int AB = 2500;      // agg blocks (4 nodes each)
static constexpr int NP = 10240;     // padded node stride
static constexpr int GG = 256;       // gemm blocks
static constexpr int NG = 625;       // 16-node groups

typedef _Float16 half8 __attribute__((ext_vector_type(8)));
typedef float f32x4 __attribute__((ext_vector_type(4)));

// ---- workspace layout (bytes); ws_size ~256 MB ----
static constexpr size_t OFF_DONE  = 0;          // uint[1]
static constexpr size_t OFF_V     = 64;         // float[256]
static constexpr size_t OFF_CNT   = 2048;       // int[10240]
static constexpr size_t OFF_DINV  = 43008;      // float[10240]
static constexpr size_t OFF_CSUM  = 83968;      // float[10240]
static constexpr size_t OFF_ELL   = 124928;     // ushort[10000*128] (j-permuted)
static constexpr size_t OFF_XH    = 2684928;    // half[10000*128]
static constexpr size_t OFF_XA    = 5244928;    // half[10000*128]
static constexpr size_t OFF_CPART = 7804928;    // ushort[128*10240]
static constexpr size_t OFF_CSP   = 10426368;   // float[64*10240]
static constexpr size_t OFF_W1T   = 13047808;   // half[256*128]

// ---- K1: slice-parallel degree count (LDS histogram) | W1^T transpose.
// int4 edge loads. Block 0 also zeroes v/done (consumed only by k_gemm). ----
__global__ __launch_bounds__(1024) void k_count(const int* __restrict__ ei,
                                                const float* __restrict__ W1,
                                                unsigned short* __restrict__ cpart,
                                                __half* __restrict__ w1t,
                                                float* __restrict__ v,
                                                unsigned int* __restrict__ done) {
    __shared__ int lh[NN];
    int t = threadIdx.x, b = blockIdx.x;
    if (b >= FB) {            // W1^T: 32 blocks, 256*128 entries
        int gid = (b - FB) * 1024 + t;
        int k = gid & 127, tc = gid >> 7;
        w1t[tc * INC + k] = __float2half(W1[k * HIDC + tc]);
        return;
    }
    if (b == 0) {
        if (t < 256) v[t] = 0.f;
        if (t == 256) *done = 0u;
    }
    for (int i = t; i < NN; i += 1024) lh[i] = 0;
    __syncthreads();
    int e0 = b * (NE / FB);
    const int4* d4 = (const int4*)(ei + NE + e0);
    for (int k = t; k < (NE / FB) / 4; k += 1024) {
        int4 dd = d4[k];
        atomicAdd(&lh[dd.x], 1);
        atomicAdd(&lh[dd.y], 1);
        atomicAdd(&lh[dd.z], 1);
        atomicAdd(&lh[dd.w], 1);
    }
    __syncthreads();
    for (int i = t; i < NN; i += 1024) cpart[b * NP + i] = (unsigned short)lh[i];
}

// ---- K2: per-node scan of partials -> per-block offsets, cnt, dinv.
// Coalesced: thread n reads cpart[b][n], consecutive threads contiguous. ----
__global__ __launch_bounds__(256) void k_scan(unsigned short* __restrict__ cpart,
                                              int* __restrict__ cnt,
                                              float* __restrict__ dinv) {
    int n = blockIdx.x * 256 + threadIdx.x;
    if (n >= NN) return;
    int run = 0;
#pragma unroll 8
    for (int b = 0; b < FB; b++) {
        int c = cpart[b * NP + n];
        cpart[b * NP + n] = (unsigned short)run;
        run += c;
    }
    cnt[n] = run;
    dinv[n] = rsqrtf((float)(1 + run));   // +1 self loop
}

// ---- K3 (fused): ELL fill (j-permuted) | csum partials | fp16 X ----
// ELL slot(pos) = (pos&3)*32 + (pos>>2): group-j entries for unroll-block i
// are contiguous at [j*32 + (i>>2), +8) -> one 16B load in k_agg.
__global__ __launch_bounds__(1024) void k_prep(const int* __restrict__ ei,
                                               const float* __restrict__ x,
                                               const float* __restrict__ dinv,
                                               const unsigned short* __restrict__ cpart,
                                               unsigned short* __restrict__ ell,
                                               float* __restrict__ cspart,
                                               __half* __restrict__ xh) {
    __shared__ int lh[NN];
    __shared__ unsigned short soff[NN];
    int t = threadIdx.x, b = blockIdx.x;
    if (b < FB) {
        for (int i = t; i < NN; i += 1024) { lh[i] = 0; soff[i] = cpart[b * NP + i]; }
        __syncthreads();
        int e0 = b * (NE / FB);
        const int4* s4 = (const int4*)(ei + e0);
        const int4* d4 = (const int4*)(ei + NE + e0);
        for (int k = t; k < (NE / FB) / 4; k += 1024) {
            int4 s = s4[k];
            int4 d = d4[k];
            int ss[4] = {s.x, s.y, s.z, s.w};
            int dd[4] = {d.x, d.y, d.z, d.w};
#pragma unroll
            for (int u = 0; u < 4; u++) {
                int pos = (int)soff[dd[u]] + atomicAdd(&lh[dd[u]], 1);
                if (pos < CAP)
                    ell[dd[u] * CAP + (pos & 3) * 32 + (pos >> 2)] = (unsigned short)ss[u];
            }
        }
    } else if (b < FB + CB) {
        int bb = b - FB;
        float* lc = (float*)lh;
        for (int i = t; i < NN; i += 1024) lc[i] = 0.f;
        __syncthreads();
        int e0 = bb * (NE / CB);
        const int4* s4 = (const int4*)(ei + e0);
        const int4* d4 = (const int4*)(ei + NE + e0);
        for (int k = t; k < (NE / CB) / 4; k += 1024) {
            int4 s = s4[k];
            int4 d = d4[k];
            atomicAdd(&lc[s.x], dinv[d.x]);
            atomicAdd(&lc[s.y], dinv[d.y]);
            atomicAdd(&lc[s.z], dinv[d.z]);
            atomicAdd(&lc[s.w], dinv[d.w]);
        }
        __syncthreads();
        for (int i = t; i < NN; i += 1024) cspart[bb * NP + i] = lc[i];
    } else {
        // xh[n,:] = fp16( dinv[n] * X[n,:] )
        int gid = (b - FB - CB) * 1024 + t;
        int i = gid * 4;
        if (i < NN * INC) {
            float4 vv = *(const float4*)(x + i);
            float dv = dinv[i >> 7];
            __half2 o[2] = {__floats2half2_rn(dv * vv.x, dv * vv.y),
                            __floats2half2_rn(dv * vv.z, dv * vv.w)};
            *(float2*)(xh + i) = *(float2*)o;
        }
    }
}

// ---- K4 (fused): aggregation gather | csum reduce ----
// Xa[n] = fp16( dinv[n]*(dinv[n]*X[n] + sum_s xh[s]) ); xh pre-scaled by dinv[s].
// Wave=node; lane = g + 16*j. NEW this round: (a) all <=4 ELL uint4 loads
// hoisted above the loop (wave-uniform predication -> scalar branches),
// breaking the per-iter ELL->gather latency chain; (b) full/tail split:
// complete 32-edge chunks run unpredicated (no cmp/cndmask, plain adds);
// only the final partial chunk runs the predicated body. Same arithmetic.
__global__ __launch_bounds__(256) void k_agg(const float* __restrict__ x,
                                             const __half* __restrict__ xh,
                                             const float* __restrict__ dinv,
                                             const int* __restrict__ cnt,
                                             const unsigned short* __restrict__ ell,
                                             const float* __restrict__ cspart,
                                             float* __restrict__ csum,
                                             __half* __restrict__ xa) {
    int b = blockIdx.x;
    if (b >= AB) {   // csum partial reduce (40 tail blocks)
        int n = (b - AB) * 256 + threadIdx.x;
        if (n < NN) {
            float s = 0.f;
#pragma unroll
            for (int bb = 0; bb < CB; bb++) s += cspart[bb * NP + n];
            csum[n] = s;
        }
        return;
    }
    int lane = threadIdx.x & 63;
    int n = b * 4 + (threadIdx.x >> 6);
    int g = lane & 15;        // 16B chunk of the 256B fp16 row
    int j = lane >> 4;        // neighbor group
    float dn = dinv[n];
    int c = cnt[n];
    int base = n * CAP + j * 32;

    // hoisted ELL loads: iteration it uses ell[base + 8*it .. +8)
    uint4 ev0, ev1, ev2, ev3;
    if (c >  0) ev0 = *(const uint4*)(ell + base);
    if (c > 32) ev1 = *(const uint4*)(ell + base + 8);
    if (c > 64) ev2 = *(const uint4*)(ell + base + 16);
    if (c > 96) ev3 = *(const uint4*)(ell + base + 24);

    float acc[8];
#pragma unroll
    for (int k = 0; k < 8; k++) acc[k] = 0.f;
    if (j == 0) {             // self loop from fp32 X (outer dn applied at end)
        const float4* x4 = (const float4*)x;
        float4 a = x4[n * 32 + 2 * g];
        float4 c4 = x4[n * 32 + 2 * g + 1];
        acc[0] = dn * a.x;  acc[1] = dn * a.y;  acc[2] = dn * a.z;  acc[3] = dn * a.w;
        acc[4] = dn * c4.x; acc[5] = dn * c4.y; acc[6] = dn * c4.z; acc[7] = dn * c4.w;
    }

    const __half* xg = xh + 8 * g;
#pragma unroll
    for (int it = 0; it < 4; it++) {
        uint4 ev = (it == 0) ? ev0 : (it == 1) ? ev1 : (it == 2) ? ev2 : ev3;
        int i0 = it * 32;
        if (i0 + 32 <= c) {
            // FULL chunk: every idx < c -> no predication, plain accumulate
            unsigned raw[8] = {ev.x & 0xffffu, ev.x >> 16, ev.y & 0xffffu, ev.y >> 16,
                               ev.z & 0xffffu, ev.z >> 16, ev.w & 0xffffu, ev.w >> 16};
            float4 xv[8];
#pragma unroll
            for (int u = 0; u < 8; u++)
                xv[u] = *(const float4*)(xg + (int)raw[u] * INC);
#pragma unroll
            for (int u = 0; u < 8; u++) {
                const __half2* h2 = (const __half2*)&xv[u];
#pragma unroll
                for (int q = 0; q < 4; q++) {
                    float2 f = __half22float2(h2[q]);
                    acc[2 * q]     += f.x;
                    acc[2 * q + 1] += f.y;
                }
            }
        } else if (i0 < c) {
            // TAIL chunk: predicated (proven form)
            unsigned raw[8] = {ev.x & 0xffffu, ev.x >> 16, ev.y & 0xffffu, ev.y >> 16,
                               ev.z & 0xffffu, ev.z >> 16, ev.w & 0xffffu, ev.w >> 16};
            int   su[8];
            float ws[8];
            float4 xv[8];
#pragma unroll
            for (int u = 0; u < 8; u++) {
                int idx = i0 + 4 * u + j;
                bool act = idx < c;
                su[u] = act ? (int)raw[u] : n;   // in-bounds safe row when inactive
                ws[u] = act ? 1.f : 0.f;
            }
#pragma unroll
            for (int u = 0; u < 8; u++)
                xv[u] = *(const float4*)(xg + su[u] * INC);
#pragma unroll
            for (int u = 0; u < 8; u++) {
                const __half2* h2 = (const __half2*)&xv[u];
#pragma unroll
                for (int q = 0; q < 4; q++) {
                    float2 f = __half22float2(h2[q]);
                    acc[2 * q]     = fmaf(ws[u], f.x, acc[2 * q]);
                    acc[2 * q + 1] = fmaf(ws[u], f.y, acc[2 * q + 1]);
                }
            }
        }
    }
#pragma unroll
    for (int k = 0; k < 8; k++) {
        acc[k] += __shfl_down(acc[k], 32);
        acc[k] += __shfl_down(acc[k], 16);
    }
    if (j == 0) {
        __half2 o[4];
#pragma unroll
        for (int q = 0; q < 4; q++)
            o[q] = __floats2half2_rn(dn * acc[2 * q], dn * acc[2 * q + 1]);
        *(float4*)(xa + n * INC + 8 * g) = *(float4*)o;
    }
}

// ---- K5: MFMA GEMM + weighted-relu reduction + fused final scalar ----
__global__ __launch_bounds__(256) void k_gemm(const __half* __restrict__ xa,
                                              const __half* __restrict__ w1t,
                                              const float* __restrict__ b1,
                                              const float* __restrict__ dinv,
                                              const float* __restrict__ csum,
                                              float* __restrict__ v,
                                              unsigned int* __restrict__ done,
                                              const float* __restrict__ W2,
                                              const float* __restrict__ b2,
                                              const float* __restrict__ fcw,
                                              const float* __restrict__ fcb,
                                              float* __restrict__ out) {
    __shared__ float vloc[HIDC];
    int t = threadIdx.x;
    int w = t >> 6;           // wave id: owns cols [64w, 64w+64)
    int lane = t & 63;
    int m = lane & 15;
    int quad = lane >> 4;
    for (int i = t; i < HIDC; i += 256) vloc[i] = 0.f;
    __syncthreads();

    float bcol[4];
#pragma unroll
    for (int tt = 0; tt < 4; tt++) bcol[tt] = b1[w * 64 + tt * 16 + m];

    const half8* xa8 = (const half8*)xa;     // 8-half (16B) granules
    const half8* w8  = (const half8*)w1t;

    for (int gidx = blockIdx.x; gidx < NG; gidx += gridDim.x) {
        int base = gidx * 16;
        f32x4 acc[4] = {{0,0,0,0},{0,0,0,0},{0,0,0,0},{0,0,0,0}};
#pragma unroll
        for (int k0 = 0; k0 < 4; k0++) {
            half8 af = xa8[(base + m) * 16 + k0 * 4 + quad];
#pragma unroll
            for (int tt = 0; tt < 4; tt++) {
                int col = w * 64 + tt * 16 + m;
                half8 bf = w8[col * 16 + k0 * 4 + quad];
                acc[tt] = __builtin_amdgcn_mfma_f32_16x16x32_f16(af, bf, acc[tt], 0, 0, 0);
            }
        }
        float cr[4];
#pragma unroll
        for (int r = 0; r < 4; r++) {
            int n = base + quad * 4 + r;
            float dnn = dinv[n];
            cr[r] = dnn * (dnn + csum[n]);
        }
#pragma unroll
        for (int tt = 0; tt < 4; tt++) {
            float p = 0.f;
#pragma unroll
            for (int r = 0; r < 4; r++)
                p += cr[r] * fmaxf(acc[tt][r] + bcol[tt], 0.f);
            p += __shfl_down(p, 16);
            p += __shfl_down(p, 32);
            if (lane < 16) vloc[w * 64 + tt * 16 + lane] += p;  // wave-disjoint cols
        }
    }
    __syncthreads();
    atomicAdd(&v[t], vloc[t]);      // device-scope, distributed across blocks
    __threadfence();
    __shared__ bool last;
    if (t == 0) {
        unsigned int old = __hip_atomic_fetch_add(done, 1u, __ATOMIC_ACQ_REL,
                                                  __HIP_MEMORY_SCOPE_AGENT);
        last = (old == gridDim.x - 1);
    }
    __syncthreads();
    if (!last) return;
    // out = (1/N)*sum_t v[t]*u[t] + b2.fc_w + fc_b,  u = W2.fc_w
    float vt = __hip_atomic_load(&v[t], __ATOMIC_ACQUIRE, __HIP_MEMORY_SCOPE_AGENT);
    __shared__ float red[256];
    float u = 0.f;
#pragma unroll 4
    for (int jj = 0; jj < OUTC; jj++) u = fmaf(W2[t * OUTC + jj], fcw[jj], u);
    float contrib = vt * u * (1.0f / (float)NN);
    if (t < OUTC) contrib += b2[t] * fcw[t];
    red[t] = contrib;
    __syncthreads();
    for (int s = 128; s > 0; s >>= 1) {
        if (t < s) red[t] += red[t + s];
        __syncthreads();
    }
    if (t == 0) out[0] = red[0] + fcb[0];
}

extern "C" void kernel_launch(void* const* d_in, const int* in_sizes, int n_in,
                              void* d_out, int out_size, void* d_ws, size_t ws_size,
                              hipStream_t stream) {
    const float* x   = (const float*)d_in[0];
    const int*   ei  = (const int*)d_in[1];
    const float* W1  = (const float*)d_in[2];
    const float* b1  = (const float*)d_in[3];
    const float* W2  = (const float*)d_in[4];
    const float* b2  = (const float*)d_in[5];
    const float* fcw = (const float*)d_in[6];
    const float* fcb = (const float*)d_in[7];
    float* out = (float*)d_out;

    char* ws = (char*)d_ws;
    unsigned int*   done   = (unsigned int*)(ws + OFF_DONE);
    float*          v      = (float*)(ws + OFF_V);
    int*            cnt    = (int*)(ws + OFF_CNT);
    float*          dinv   = (float*)(ws + OFF_DINV);
    float*          csum   = (float*)(ws + OFF_CSUM);
    unsigned short* ell    = (unsigned short*)(ws + OFF_ELL);
    __half*         xh     = (__half*)(ws + OFF_XH);
    __half*         xa     = (__half*)(ws + OFF_XA);
    unsigned short* cpart  = (unsigned short*)(ws + OFF_CPART);
    float*          cspart = (float*)(ws + OFF_CSP);
    __half*         w1t    = (__half*)(ws + OFF_W1T);

    k_count<<<FB + TB, 1024, 0, stream>>>(ei, W1, cpart, w1t, v, done);
    k_scan<<<40, 256, 0, stream>>>(cpart, cnt, dinv);
    k_prep<<<FB + CB + HB, 1024, 0, stream>>>(ei, x, dinv, cpart, ell,
                                              cspart, xh);
    k_agg<<<AB + 40, 256, 0, stream>>>(x, xh, dinv, cnt, ell, cspart, csum, xa);
    k_gemm<<<GG, 256, 0, stream>>>(xa, w1t, b1, dinv, csum, v, done,
                                   W2, b2, fcw, fcb, out);
}